// Round 1
// baseline (1850.608 us; speedup 1.0000x reference)
//
#include <hip/hip_runtime.h>
#include <hip/hip_bf16.h>
#include <math.h>

// Problem dims (fixed by reference setup_inputs)
#define D_DIM 512
#define LX 2048
#define LY 2048
#define NB 8

// ---------------------------------------------------------------------------
// Kernel 1: xw[b,i,e] = sum_d x[b,i,d] * Wb[e,d]
// Treated as flat GEMM: M = NB*LX = 16384, N = D = 512, K = D = 512.
// Both operands are K-contiguous row-major (NT GEMM) -> coalesced float4 loads.
// 64x64 block tile, BK=16, 256 threads, 4x4 micro-tile per thread.
// ---------------------------------------------------------------------------
__global__ __launch_bounds__(256) void xw_gemm_k(
    const float* __restrict__ x, const float* __restrict__ Wb,
    float* __restrict__ xw)
{
    // k-major LDS tiles, padded stride 68 floats: keeps float4 reads 16B-aligned
    // and bank spread (68 % 32 == 4 -> bank = 4*(k+m/4) pattern, worst 2-way).
    __shared__ float As[16][68];
    __shared__ float Bs[16][68];

    const int tid = threadIdx.x;
    const int bm  = blockIdx.x * 64;
    const int bn  = blockIdx.y * 64;
    const int tm  = (tid & 15) * 4;   // 4 consecutive output rows
    const int tn  = (tid >> 4) * 4;   // 4 consecutive output cols
    const int lrow = tid >> 2;        // 0..63 staging row
    const int lk   = (tid & 3) * 4;   // 0,4,8,12 staging k

    const float* ag = x  + (size_t)(bm + lrow) * D_DIM + lk;
    const float* bg = Wb + (size_t)(bn + lrow) * D_DIM + lk;

    float acc[4][4] = {};

    for (int kt = 0; kt < D_DIM; kt += 16) {
        const float4 av = *(const float4*)(ag + kt);
        const float4 bv = *(const float4*)(bg + kt);
        __syncthreads();  // protect previous iteration's LDS reads
        As[lk+0][lrow] = av.x; As[lk+1][lrow] = av.y;
        As[lk+2][lrow] = av.z; As[lk+3][lrow] = av.w;
        Bs[lk+0][lrow] = bv.x; Bs[lk+1][lrow] = bv.y;
        Bs[lk+2][lrow] = bv.z; Bs[lk+3][lrow] = bv.w;
        __syncthreads();
        #pragma unroll
        for (int k = 0; k < 16; ++k) {
            const float4 a = *(const float4*)&As[k][tm];
            const float4 b = *(const float4*)&Bs[k][tn];
            const float* ap = (const float*)&a;
            const float* bp = (const float*)&b;
            #pragma unroll
            for (int i = 0; i < 4; ++i)
                #pragma unroll
                for (int jj = 0; jj < 4; ++jj)
                    acc[i][jj] = fmaf(ap[i], bp[jj], acc[i][jj]);
        }
    }

    #pragma unroll
    for (int i = 0; i < 4; ++i) {
        float4 c = make_float4(acc[i][0], acc[i][1], acc[i][2], acc[i][3]);
        *(float4*)&xw[(size_t)(bm + tm + i) * D_DIM + bn + tn] = c;
    }
}

// ---------------------------------------------------------------------------
// Kernel 2: flash-style bilinear attention (fp32).
//   S[j,c] = sum_d y[b,jrow,d] * xw[b,crow,d]   (online softmax over c)
//   O[j,:] = sum_c P[j,c] * x[b,crow,:]
// Block: 256 threads, TY=16 y-rows, TX=64 x-cols per tile.
// Thread (j = tid/16, tc = tid%16): owns S[j][tc*4..+3] and O[j][tc*4 + 64*ii].
// Y tile fully LDS-resident; XW staged k-major (transposed) per 64-k chunk;
// X staged 8 rows at a time for the PV accumulation.
// ---------------------------------------------------------------------------
#define TY 16
#define TX 64
#define CK 64

__global__ __launch_bounds__(256) void flash_k(
    const float* __restrict__ x, const float* __restrict__ y,
    const float* __restrict__ xw, float* __restrict__ out)
{
    __shared__ float Yl[TY][516];   // stride 516: bank = (4j + k) % 32, conflict-free
    __shared__ float XWl[CK][68];   // k-major: read XWl[k][c0] float4, banks spread
    __shared__ float Pl[TY][68];
    __shared__ float Xl[8][512];

    const int tid = threadIdx.x;
    const int b   = blockIdx.y;
    const int jt  = blockIdx.x;
    const int j   = tid >> 4;       // 0..15 y-row within tile
    const int tc  = tid & 15;       // 0..15
    const int c0  = tc * 4;

    // Stage Y tile (read after first staging __syncthreads below)
    {
        const float* yg = y + (size_t)(b * LY + jt * TY + j) * D_DIM;
        #pragma unroll
        for (int ii = 0; ii < 8; ++ii)
            *(float4*)&Yl[j][tc * 4 + 64 * ii] = *(const float4*)(yg + tc * 4 + 64 * ii);
    }

    float4 o[8];
    #pragma unroll
    for (int ii = 0; ii < 8; ++ii) o[ii] = make_float4(0.f, 0.f, 0.f, 0.f);
    float m = -INFINITY;
    float l = 0.f;

    const size_t xbase = (size_t)b * LX * D_DIM;

    for (int xt = 0; xt < LX / TX; ++xt) {
        float sa[4] = {0.f, 0.f, 0.f, 0.f};

        // ---- S = Y . XW^T over D in CK chunks ----
        for (int kc = 0; kc < D_DIM; kc += CK) {
            const int sc  = tid >> 2;         // 0..63: xw row within x-tile
            const int skq = (tid & 3) * 4;    // 0,4,8,12
            const float* xwg = xw + xbase + (size_t)(xt * TX + sc) * D_DIM + kc + skq;
            const float4 t0 = *(const float4*)(xwg + 0);
            const float4 t1 = *(const float4*)(xwg + 16);
            const float4 t2 = *(const float4*)(xwg + 32);
            const float4 t3 = *(const float4*)(xwg + 48);
            __syncthreads();
            XWl[skq+ 0][sc] = t0.x; XWl[skq+ 1][sc] = t0.y; XWl[skq+ 2][sc] = t0.z; XWl[skq+ 3][sc] = t0.w;
            XWl[skq+16][sc] = t1.x; XWl[skq+17][sc] = t1.y; XWl[skq+18][sc] = t1.z; XWl[skq+19][sc] = t1.w;
            XWl[skq+32][sc] = t2.x; XWl[skq+33][sc] = t2.y; XWl[skq+34][sc] = t2.z; XWl[skq+35][sc] = t2.w;
            XWl[skq+48][sc] = t3.x; XWl[skq+49][sc] = t3.y; XWl[skq+50][sc] = t3.z; XWl[skq+51][sc] = t3.w;
            __syncthreads();
            #pragma unroll
            for (int k4 = 0; k4 < CK / 4; ++k4) {
                const float4 yv = *(const float4*)&Yl[j][kc + k4 * 4];
                const float* yp = (const float*)&yv;
                #pragma unroll
                for (int s = 0; s < 4; ++s) {
                    const float4 xv = *(const float4*)&XWl[k4 * 4 + s][c0];
                    sa[0] = fmaf(yp[s], xv.x, sa[0]);
                    sa[1] = fmaf(yp[s], xv.y, sa[1]);
                    sa[2] = fmaf(yp[s], xv.z, sa[2]);
                    sa[3] = fmaf(yp[s], xv.w, sa[3]);
                }
            }
        }

        // ---- online softmax update (row group = 16 contiguous lanes) ----
        float tmax = fmaxf(fmaxf(sa[0], sa[1]), fmaxf(sa[2], sa[3]));
        #pragma unroll
        for (int w = 1; w < 16; w <<= 1)
            tmax = fmaxf(tmax, __shfl_xor(tmax, w, 64));
        const float mnew  = fmaxf(m, tmax);
        const float scale = __expf(m - mnew);   // exp(-inf)=0 on first tile
        const float p0 = __expf(sa[0] - mnew);
        const float p1 = __expf(sa[1] - mnew);
        const float p2 = __expf(sa[2] - mnew);
        const float p3 = __expf(sa[3] - mnew);
        float ts = p0 + p1 + p2 + p3;
        #pragma unroll
        for (int w = 1; w < 16; w <<= 1)
            ts += __shfl_xor(ts, w, 64);
        l = l * scale + ts;
        m = mnew;
        #pragma unroll
        for (int ii = 0; ii < 8; ++ii) {
            o[ii].x *= scale; o[ii].y *= scale;
            o[ii].z *= scale; o[ii].w *= scale;
        }
        *(float4*)&Pl[j][c0] = make_float4(p0, p1, p2, p3);
        // Pl read only after the next __syncthreads (X staging) -> safe.

        // ---- O += P . X, 8 x-rows per chunk ----
        for (int cc = 0; cc < TX / 8; ++cc) {
            const int xr = tid >> 5;          // 0..7
            const int xq = (tid & 31) * 4;    // 0..124
            const float* xg = x + xbase + (size_t)(xt * TX + cc * 8 + xr) * D_DIM + xq;
            const float4 x0 = *(const float4*)(xg + 0);
            const float4 x1 = *(const float4*)(xg + 128);
            const float4 x2 = *(const float4*)(xg + 256);
            const float4 x3 = *(const float4*)(xg + 384);
            __syncthreads();  // protect previous chunk's Xl reads (and order Pl write->read)
            *(float4*)&Xl[xr][xq +   0] = x0;
            *(float4*)&Xl[xr][xq + 128] = x1;
            *(float4*)&Xl[xr][xq + 256] = x2;
            *(float4*)&Xl[xr][xq + 384] = x3;
            __syncthreads();
            #pragma unroll
            for (int c = 0; c < 8; ++c) {
                const float pv = Pl[j][cc * 8 + c];
                #pragma unroll
                for (int ii = 0; ii < 8; ++ii) {
                    const float4 xv = *(const float4*)&Xl[c][tc * 4 + 64 * ii];
                    o[ii].x = fmaf(pv, xv.x, o[ii].x);
                    o[ii].y = fmaf(pv, xv.y, o[ii].y);
                    o[ii].z = fmaf(pv, xv.z, o[ii].z);
                    o[ii].w = fmaf(pv, xv.w, o[ii].w);
                }
            }
        }
    }

    const float inv = 1.0f / l;
    float* og = out + (size_t)(b * LY + jt * TY + j) * D_DIM;
    #pragma unroll
    for (int ii = 0; ii < 8; ++ii) {
        float4 v = o[ii];
        v.x *= inv; v.y *= inv; v.z *= inv; v.w *= inv;
        *(float4*)(og + tc * 4 + 64 * ii) = v;
    }
}

// ---------------------------------------------------------------------------
extern "C" void kernel_launch(void* const* d_in, const int* in_sizes, int n_in,
                              void* d_out, int out_size, void* d_ws, size_t ws_size,
                              hipStream_t stream)
{
    const float* x  = (const float*)d_in[0];
    const float* y  = (const float*)d_in[1];
    const float* Wb = (const float*)d_in[2];
    float* out = (float*)d_out;
    float* xw  = (float*)d_ws;   // NB*LX*D floats = 33.5 MB scratch

    dim3 g1(NB * LX / 64, D_DIM / 64);   // (256, 8)
    xw_gemm_k<<<g1, 256, 0, stream>>>(x, Wb, xw);

    dim3 g2(LY / TY, NB);                // (128, 8)
    flash_k<<<g2, 256, 0, stream>>>(x, y, xw, out);
}

// Round 2
// 395.685 us; speedup vs baseline: 4.6770x; 4.6770x over previous
//
#include <hip/hip_runtime.h>
#include <hip/hip_bf16.h>
#include <math.h>

#define D_DIM 512
#define LX 2048
#define LY 2048
#define NB 8

typedef float f32x4 __attribute__((ext_vector_type(4)));
typedef __bf16 bf16x8 __attribute__((ext_vector_type(8)));

__device__ __forceinline__ unsigned short f2bf_rn(float f) {
    unsigned u = __float_as_uint(f);
    unsigned r = (u + 0x7fffu + ((u >> 16) & 1u)) >> 16;
    return (unsigned short)r;
}
__device__ __forceinline__ float bf2f(unsigned short h) {
    return __uint_as_float(((unsigned)h) << 16);
}
__device__ __forceinline__ void async16(void* lds, const void* g) {
    __builtin_amdgcn_global_load_lds(
        (const __attribute__((address_space(1))) void*)g,
        (__attribute__((address_space(3))) void*)lds, 16, 0, 0);
}
__device__ __forceinline__ bf16x8 ldfrag(const char* p) {
    return *(const bf16x8*)p;
}

// ---------------------------------------------------------------------------
// k0a: row-major fp32 [R][512] -> frag-order hi/lo bf16.
// frag block fb = r16*16 + k32 ; within block: lane = row%16 + 16*((k%32)/8),
// elems = k%8 (8 consecutive k). 1024 B per block, lane-linear.
// ---------------------------------------------------------------------------
__global__ __launch_bounds__(256) void repack_hilo_k(
    const float* __restrict__ src, unsigned short* __restrict__ dh,
    unsigned short* __restrict__ dl, int nfb)
{
    int fbid = blockIdx.x * 4 + (threadIdx.x >> 6);
    if (fbid >= nfb) return;
    int lane = threadIdx.x & 63;
    int r16 = fbid >> 4, k32 = fbid & 15;          // K=512 -> 16 k32 blocks
    int row = r16 * 16 + (lane & 15);
    int col = k32 * 32 + (lane >> 4) * 8;
    const float* s = src + (size_t)row * D_DIM + col;
    float4 v0 = *(const float4*)s;
    float4 v1 = *(const float4*)(s + 4);
    float vv[8] = {v0.x, v0.y, v0.z, v0.w, v1.x, v1.y, v1.z, v1.w};
    unsigned hh[4], ll[4];
    #pragma unroll
    for (int k = 0; k < 4; ++k) {
        unsigned short ha = f2bf_rn(vv[2*k]),   hb = f2bf_rn(vv[2*k+1]);
        unsigned short la = f2bf_rn(vv[2*k]   - bf2f(ha));
        unsigned short lb = f2bf_rn(vv[2*k+1] - bf2f(hb));
        hh[k] = (unsigned)ha | ((unsigned)hb << 16);
        ll[k] = (unsigned)la | ((unsigned)lb << 16);
    }
    size_t off = (size_t)fbid * 512 + lane * 8;
    *(uint4*)(dh + off) = make_uint4(hh[0], hh[1], hh[2], hh[3]);
    *(uint4*)(dl + off) = make_uint4(ll[0], ll[1], ll[2], ll[3]);
}

// ---------------------------------------------------------------------------
// k0d: x[b][c][dd] fp32 -> xtf bf16 frag-order of x^T (rows=dd, k=c):
// layout [(b*32+dd16)*64 + c32] blocks of [lane][8], lane = dd%16+16*((c%32)/8)
// ---------------------------------------------------------------------------
__global__ __launch_bounds__(256) void xt_repack_k(
    const float* __restrict__ x, unsigned short* __restrict__ xtf)
{
    __shared__ unsigned short T2[64][72];   // [dd_local][c_local]
    int ct = blockIdx.x, dt = blockIdx.y, b = blockIdx.z;
    int tid = threadIdx.x;
    const float* xb = x + (size_t)b * LX * D_DIM;
    int rc = tid >> 4;               // c_local base
    int d4 = (tid & 15) * 4;         // dd_local
    #pragma unroll
    for (int i = 0; i < 4; ++i) {
        int cl = rc + i * 16;
        float4 v = *(const float4*)(xb + (size_t)(ct * 64 + cl) * D_DIM + dt * 64 + d4);
        T2[d4 + 0][cl] = f2bf_rn(v.x);
        T2[d4 + 1][cl] = f2bf_rn(v.y);
        T2[d4 + 2][cl] = f2bf_rn(v.z);
        T2[d4 + 3][cl] = f2bf_rn(v.w);
    }
    __syncthreads();
    #pragma unroll
    for (int si = 0; si < 2; ++si) {
        int s = tid + si * 256;
        int fb = s >> 6, lane = s & 63;
        int dd16l = fb >> 1, c32l = fb & 1;
        int ddl = dd16l * 16 + (lane & 15);
        int cl  = c32l * 32 + (lane >> 4) * 8;
        uint4 v = *(const uint4*)&T2[ddl][cl];
        size_t off = ((size_t)((b * 32 + dt * 4 + dd16l) * 64 + (ct * 2 + c32l)) * 64 + lane) * 8;
        *(uint4*)(xtf + off) = v;
    }
}

// ---------------------------------------------------------------------------
// k1: xw = x @ Wb^T via 4-term hi/lo MFMA. M=16384, N=512, K=512.
// Block 128x64, 4 waves (wave: 32 M x 64 N). Emits xwf hi/lo frag-order.
// ---------------------------------------------------------------------------
__global__ __launch_bounds__(256, 2) void xw_mfma_k(
    const unsigned short* __restrict__ xfh, const unsigned short* __restrict__ xfl,
    const unsigned short* __restrict__ wfh, const unsigned short* __restrict__ wfl,
    unsigned short* __restrict__ xwfh, unsigned short* __restrict__ xwfl)
{
    __shared__ char smem[49152];   // Ah 0, Al 16K, Bh 32K, Bl 40K ; epi fp32 [128][68]
    const int tid = threadIdx.x, lane = tid & 63, w = tid >> 6;
    const int Mt = blockIdx.x, Nt = blockIdx.y;
    f32x4 acc[2][4];
    #pragma unroll
    for (int m = 0; m < 2; ++m)
        #pragma unroll
        for (int n = 0; n < 4; ++n) acc[m][n] = (f32x4){0.f, 0.f, 0.f, 0.f};

    for (int kc = 0; kc < 8; ++kc) {
        __syncthreads();
        #pragma unroll
        for (int i = 0; i < 8; ++i) {               // A: 32 segs
            int seg = w + 4 * i;
            int h = seg >> 4, c16l = (seg >> 1) & 7, k32l = seg & 1;
            size_t fb = (size_t)(Mt * 8 + c16l) * 16 + kc * 2 + k32l;
            const unsigned short* src = (h ? xfl : xfh) + fb * 512 + lane * 8;
            char* dst = smem + (h ? 16384 : 0) + ((c16l * 2 + k32l) * 64 + lane) * 16;
            async16(dst, src);
        }
        #pragma unroll
        for (int i = 0; i < 4; ++i) {               // B: 16 segs
            int seg = w + 4 * i;
            int h = seg >> 3, n16l = (seg >> 1) & 3, k32l = seg & 1;
            size_t fb = (size_t)(Nt * 4 + n16l) * 16 + kc * 2 + k32l;
            const unsigned short* src = (h ? wfl : wfh) + fb * 512 + lane * 8;
            char* dst = smem + (h ? 40960 : 32768) + ((n16l * 2 + k32l) * 64 + lane) * 16;
            async16(dst, src);
        }
        __syncthreads();
        #pragma unroll
        for (int ks = 0; ks < 2; ++ks) {
            bf16x8 ah[2], al[2], bh[4], bl[4];
            #pragma unroll
            for (int m = 0; m < 2; ++m) {
                int c16l = w * 2 + m;
                ah[m] = ldfrag(smem +     0 + ((c16l * 2 + ks) * 64 + lane) * 16);
                al[m] = ldfrag(smem + 16384 + ((c16l * 2 + ks) * 64 + lane) * 16);
            }
            #pragma unroll
            for (int n = 0; n < 4; ++n) {
                bh[n] = ldfrag(smem + 32768 + ((n * 2 + ks) * 64 + lane) * 16);
                bl[n] = ldfrag(smem + 40960 + ((n * 2 + ks) * 64 + lane) * 16);
            }
            #pragma unroll
            for (int m = 0; m < 2; ++m)
                #pragma unroll
                for (int n = 0; n < 4; ++n) {
                    acc[m][n] = __builtin_amdgcn_mfma_f32_16x16x32_bf16(ah[m], bh[n], acc[m][n], 0, 0, 0);
                    acc[m][n] = __builtin_amdgcn_mfma_f32_16x16x32_bf16(ah[m], bl[n], acc[m][n], 0, 0, 0);
                    acc[m][n] = __builtin_amdgcn_mfma_f32_16x16x32_bf16(al[m], bh[n], acc[m][n], 0, 0, 0);
                    acc[m][n] = __builtin_amdgcn_mfma_f32_16x16x32_bf16(al[m], bl[n], acc[m][n], 0, 0, 0);
                }
        }
    }
    // epilogue: LDS transpose -> frag-order hi/lo
    __syncthreads();
    float* E = (float*)smem;                        // [128][68]
    const int q = lane >> 4, c15 = lane & 15;
    #pragma unroll
    for (int m = 0; m < 2; ++m)
        #pragma unroll
        for (int n = 0; n < 4; ++n)
            #pragma unroll
            for (int r = 0; r < 4; ++r)
                E[(w * 32 + m * 16 + q * 4 + r) * 68 + n * 16 + c15] = acc[m][n][r];
    __syncthreads();
    #pragma unroll
    for (int i = 0; i < 4; ++i) {
        int s = tid + i * 256;
        int c16l = s >> 7, e32l = (s >> 6) & 1, lp = s & 63;
        int row = c16l * 16 + (lp & 15), col = e32l * 32 + (lp >> 4) * 8;
        const float* sp = E + row * 68 + col;
        unsigned hh[4], ll[4];
        #pragma unroll
        for (int k = 0; k < 4; ++k) {
            float a = sp[2 * k], bq = sp[2 * k + 1];
            unsigned short ha = f2bf_rn(a), hb = f2bf_rn(bq);
            unsigned short la = f2bf_rn(a - bf2f(ha)), lb = f2bf_rn(bq - bf2f(hb));
            hh[k] = (unsigned)ha | ((unsigned)hb << 16);
            ll[k] = (unsigned)la | ((unsigned)lb << 16);
        }
        size_t fb = (size_t)(Mt * 8 + c16l) * 16 + (Nt * 2 + e32l);
        *(uint4*)(xwfh + fb * 512 + lp * 8) = make_uint4(hh[0], hh[1], hh[2], hh[3]);
        *(uint4*)(xwfl + fb * 512 + lp * 8) = make_uint4(ll[0], ll[1], ll[2], ll[3]);
    }
}

// ---------------------------------------------------------------------------
// k2: flash bilinear attention, MFMA. Block: 32 j x 128 c, 4 waves.
// Wave: S rows 0..31 x cols [w*32,+32) (hi/lo 4-term); O cols [w*128,+128).
// LDS 48 KB: XWh 0 /XWl 16K (Xt aliases 0..32K), Yh 32K (red aliases), Yl 36K, Pf 40K.
// ---------------------------------------------------------------------------
__global__ __launch_bounds__(256, 2) void flash_mfma_k(
    const unsigned short* __restrict__ yfh, const unsigned short* __restrict__ yfl,
    const unsigned short* __restrict__ xwfh, const unsigned short* __restrict__ xwfl,
    const unsigned short* __restrict__ xtf, float* __restrict__ out)
{
    __shared__ char smem[49152];
    const int tid = threadIdx.x, lane = tid & 63, w = tid >> 6;
    const int jt = blockIdx.x, b = blockIdx.y;
    const int q = lane >> 4, c15 = lane & 15;

    f32x4 o[2][8];
    #pragma unroll
    for (int m = 0; m < 2; ++m)
        #pragma unroll
        for (int n = 0; n < 8; ++n) o[m][n] = (f32x4){0.f, 0.f, 0.f, 0.f};
    float m_run[2][4], l_run[2][4];
    #pragma unroll
    for (int m = 0; m < 2; ++m)
        #pragma unroll
        for (int r = 0; r < 4; ++r) { m_run[m][r] = -INFINITY; l_run[m][r] = 0.f; }

    for (int xt = 0; xt < 16; ++xt) {
        f32x4 s[2][2];
        #pragma unroll
        for (int m = 0; m < 2; ++m)
            #pragma unroll
            for (int n = 0; n < 2; ++n) s[m][n] = (f32x4){0.f, 0.f, 0.f, 0.f};

        // ---- S phase: K=512 in 8 chunks of 64 ----
        for (int kc = 0; kc < 8; ++kc) {
            __syncthreads();
            #pragma unroll
            for (int i = 0; i < 8; ++i) {           // XW: 32 segs
                int seg = w + 4 * i;
                int h = seg >> 4, c16l = (seg >> 1) & 7, k32l = seg & 1;
                size_t fb = (size_t)(b * 128 + xt * 8 + c16l) * 16 + kc * 2 + k32l;
                const unsigned short* src = (h ? xwfl : xwfh) + fb * 512 + lane * 8;
                char* dst = smem + (h ? 16384 : 0) + ((c16l * 2 + k32l) * 64 + lane) * 16;
                async16(dst, src);
            }
            #pragma unroll
            for (int i = 0; i < 2; ++i) {           // Y: 8 segs
                int seg = w + 4 * i;
                int h = seg >> 2, j16l = (seg >> 1) & 1, k32l = seg & 1;
                size_t fb = (size_t)(b * 128 + jt * 2 + j16l) * 16 + kc * 2 + k32l;
                const unsigned short* src = (h ? yfl : yfh) + fb * 512 + lane * 8;
                char* dst = smem + (h ? 36864 : 32768) + ((j16l * 2 + k32l) * 64 + lane) * 16;
                async16(dst, src);
            }
            __syncthreads();
            #pragma unroll
            for (int ks = 0; ks < 2; ++ks) {
                bf16x8 ah[2], al[2], bh[2], bl[2];
                #pragma unroll
                for (int m = 0; m < 2; ++m) {
                    ah[m] = ldfrag(smem + 32768 + ((m * 2 + ks) * 64 + lane) * 16);
                    al[m] = ldfrag(smem + 36864 + ((m * 2 + ks) * 64 + lane) * 16);
                }
                #pragma unroll
                for (int n = 0; n < 2; ++n) {
                    int c16l = w * 2 + n;
                    bh[n] = ldfrag(smem +     0 + ((c16l * 2 + ks) * 64 + lane) * 16);
                    bl[n] = ldfrag(smem + 16384 + ((c16l * 2 + ks) * 64 + lane) * 16);
                }
                #pragma unroll
                for (int m = 0; m < 2; ++m)
                    #pragma unroll
                    for (int n = 0; n < 2; ++n) {
                        s[m][n] = __builtin_amdgcn_mfma_f32_16x16x32_bf16(ah[m], bh[n], s[m][n], 0, 0, 0);
                        s[m][n] = __builtin_amdgcn_mfma_f32_16x16x32_bf16(ah[m], bl[n], s[m][n], 0, 0, 0);
                        s[m][n] = __builtin_amdgcn_mfma_f32_16x16x32_bf16(al[m], bh[n], s[m][n], 0, 0, 0);
                        s[m][n] = __builtin_amdgcn_mfma_f32_16x16x32_bf16(al[m], bl[n], s[m][n], 0, 0, 0);
                    }
            }
        }

        // ---- online softmax (rows j = m*16 + q*4 + r) ----
        float pmax[2][4];
        #pragma unroll
        for (int m = 0; m < 2; ++m)
            #pragma unroll
            for (int r = 0; r < 4; ++r) pmax[m][r] = fmaxf(s[m][0][r], s[m][1][r]);
        __syncthreads();                     // (a): all S reads of XW/Y done
        #pragma unroll
        for (int d = 1; d < 16; d <<= 1)
            #pragma unroll
            for (int m = 0; m < 2; ++m)
                #pragma unroll
                for (int r = 0; r < 4; ++r)
                    pmax[m][r] = fmaxf(pmax[m][r], __shfl_xor(pmax[m][r], d, 64));
        float* red_max = (float*)(smem + 32768);
        float* red_sum = (float*)(smem + 33280);
        if (c15 == 0) {
            #pragma unroll
            for (int m = 0; m < 2; ++m)
                #pragma unroll
                for (int r = 0; r < 4; ++r)
                    red_max[w * 32 + m * 16 + q * 4 + r] = pmax[m][r];
        }
        __syncthreads();                     // (b)
        float mnew[2][4], alpha[2][4];
        #pragma unroll
        for (int m = 0; m < 2; ++m)
            #pragma unroll
            for (int r = 0; r < 4; ++r) {
                int j = m * 16 + q * 4 + r;
                float t = red_max[j];
                t = fmaxf(t, red_max[32 + j]);
                t = fmaxf(t, red_max[64 + j]);
                t = fmaxf(t, red_max[96 + j]);
                float mn = fmaxf(m_run[m][r], t);
                mnew[m][r] = mn;
                alpha[m][r] = __expf(m_run[m][r] - mn);
                m_run[m][r] = mn;
            }
        unsigned short* Pf = (unsigned short*)(smem + 40960);
        float psum[2][4];
        #pragma unroll
        for (int m = 0; m < 2; ++m)
            #pragma unroll
            for (int r = 0; r < 4; ++r) {
                float p0 = __expf(s[m][0][r] - mnew[m][r]);
                float p1 = __expf(s[m][1][r] - mnew[m][r]);
                s[m][0][r] = p0; s[m][1][r] = p1;
                psum[m][r] = p0 + p1;
            }
        #pragma unroll
        for (int d = 1; d < 16; d <<= 1)
            #pragma unroll
            for (int m = 0; m < 2; ++m)
                #pragma unroll
                for (int r = 0; r < 4; ++r)
                    psum[m][r] += __shfl_xor(psum[m][r], d, 64);
        if (c15 == 0) {
            #pragma unroll
            for (int m = 0; m < 2; ++m)
                #pragma unroll
                for (int r = 0; r < 4; ++r)
                    red_sum[w * 32 + m * 16 + q * 4 + r] = psum[m][r];
        }
        #pragma unroll
        for (int m = 0; m < 2; ++m)
            #pragma unroll
            for (int n = 0; n < 2; ++n)
                #pragma unroll
                for (int r = 0; r < 4; ++r) {
                    int cl = n * 16 + c15;
                    int lp = (q * 4 + r) + 16 * (cl >> 3);
                    Pf[((m * 4 + w) * 64 + lp) * 8 + (cl & 7)] = f2bf_rn(s[m][n][r]);
                }
        __syncthreads();                     // (c): Pf + red_sum visible
        #pragma unroll
        for (int m = 0; m < 2; ++m)
            #pragma unroll
            for (int r = 0; r < 4; ++r) {
                int j = m * 16 + q * 4 + r;
                float ts = red_sum[j] + red_sum[32 + j] + red_sum[64 + j] + red_sum[96 + j];
                l_run[m][r] = l_run[m][r] * alpha[m][r] + ts;
            }
        #pragma unroll
        for (int m = 0; m < 2; ++m)
            #pragma unroll
            for (int n = 0; n < 8; ++n)
                #pragma unroll
                for (int r = 0; r < 4; ++r) o[m][n][r] *= alpha[m][r];

        // ---- PV: c-tile of 128 in 4 chunks of 32 (Xt aliases XW space) ----
        for (int cc = 0; cc < 4; ++cc) {
            #pragma unroll
            for (int i = 0; i < 8; ++i) {           // Xt: 32 segs
                int dd16 = w + 4 * i;
                size_t off = ((size_t)(b * 32 + dd16) * 64 + (xt * 4 + cc)) * 512 + lane * 8;
                async16(smem + dd16 * 1024 + lane * 16, xtf + off);
            }
            __syncthreads();
            bf16x8 pa[2];
            pa[0] = ldfrag(smem + 40960 + ((0 * 4 + cc) * 64 + lane) * 16);
            pa[1] = ldfrag(smem + 40960 + ((1 * 4 + cc) * 64 + lane) * 16);
            #pragma unroll
            for (int n = 0; n < 8; ++n) {
                bf16x8 xb = ldfrag(smem + (w * 8 + n) * 1024 + lane * 16);
                o[0][n] = __builtin_amdgcn_mfma_f32_16x16x32_bf16(pa[0], xb, o[0][n], 0, 0, 0);
                o[1][n] = __builtin_amdgcn_mfma_f32_16x16x32_bf16(pa[1], xb, o[1][n], 0, 0, 0);
            }
            __syncthreads();
        }
    }

    // ---- epilogue ----
    #pragma unroll
    for (int m = 0; m < 2; ++m)
        #pragma unroll
        for (int r = 0; r < 4; ++r) {
            float inv = 1.0f / l_run[m][r];
            int j = jt * 32 + m * 16 + q * 4 + r;
            #pragma unroll
            for (int n = 0; n < 8; ++n) {
                int dd = w * 128 + n * 16 + c15;
                out[((size_t)(b * 2048 + j)) * 512 + dd] = o[m][n][r] * inv;
            }
        }
}

// ---------------------------------------------------------------------------
// Fallback fp32 path (R1 kernels) if ws_size is too small for the fast path.
// ---------------------------------------------------------------------------
__global__ __launch_bounds__(256) void xw_gemm_fb(
    const float* __restrict__ x, const float* __restrict__ Wb, float* __restrict__ xw)
{
    __shared__ float As[16][68];
    __shared__ float Bs[16][68];
    const int tid = threadIdx.x;
    const int bm = blockIdx.x * 64, bn = blockIdx.y * 64;
    const int tm = (tid & 15) * 4, tn = (tid >> 4) * 4;
    const int lrow = tid >> 2, lk = (tid & 3) * 4;
    const float* ag = x  + (size_t)(bm + lrow) * D_DIM + lk;
    const float* bg = Wb + (size_t)(bn + lrow) * D_DIM + lk;
    float acc[4][4] = {};
    for (int kt = 0; kt < D_DIM; kt += 16) {
        const float4 av = *(const float4*)(ag + kt);
        const float4 bv = *(const float4*)(bg + kt);
        __syncthreads();
        As[lk+0][lrow] = av.x; As[lk+1][lrow] = av.y; As[lk+2][lrow] = av.z; As[lk+3][lrow] = av.w;
        Bs[lk+0][lrow] = bv.x; Bs[lk+1][lrow] = bv.y; Bs[lk+2][lrow] = bv.z; Bs[lk+3][lrow] = bv.w;
        __syncthreads();
        #pragma unroll
        for (int k = 0; k < 16; ++k) {
            const float4 a = *(const float4*)&As[k][tm];
            const float4 bq = *(const float4*)&Bs[k][tn];
            const float* ap = (const float*)&a;
            const float* bp = (const float*)&bq;
            #pragma unroll
            for (int i = 0; i < 4; ++i)
                #pragma unroll
                for (int jj = 0; jj < 4; ++jj)
                    acc[i][jj] = fmaf(ap[i], bp[jj], acc[i][jj]);
        }
    }
    #pragma unroll
    for (int i = 0; i < 4; ++i)
        *(float4*)&xw[(size_t)(bm + tm + i) * D_DIM + bn + tn] =
            make_float4(acc[i][0], acc[i][1], acc[i][2], acc[i][3]);
}

__global__ __launch_bounds__(256) void flash_fb(
    const float* __restrict__ x, const float* __restrict__ y,
    const float* __restrict__ xw, float* __restrict__ out)
{
    __shared__ float Yl[16][516];
    __shared__ float XWl[64][68];
    __shared__ float Pl[16][68];
    __shared__ float Xl[8][512];
    const int tid = threadIdx.x, b = blockIdx.y, jtb = blockIdx.x;
    const int j = tid >> 4, tc = tid & 15, c0 = tc * 4;
    {
        const float* yg = y + (size_t)(b * LY + jtb * 16 + j) * D_DIM;
        #pragma unroll
        for (int ii = 0; ii < 8; ++ii)
            *(float4*)&Yl[j][tc * 4 + 64 * ii] = *(const float4*)(yg + tc * 4 + 64 * ii);
    }
    float4 o[8];
    #pragma unroll
    for (int ii = 0; ii < 8; ++ii) o[ii] = make_float4(0.f, 0.f, 0.f, 0.f);
    float m = -INFINITY, l = 0.f;
    const size_t xbase = (size_t)b * LX * D_DIM;
    for (int xtt = 0; xtt < LX / 64; ++xtt) {
        float sa[4] = {0.f, 0.f, 0.f, 0.f};
        for (int kcc = 0; kcc < D_DIM; kcc += 64) {
            const int sc = tid >> 2, skq = (tid & 3) * 4;
            const float* xwg = xw + xbase + (size_t)(xtt * 64 + sc) * D_DIM + kcc + skq;
            const float4 t0 = *(const float4*)(xwg + 0);
            const float4 t1 = *(const float4*)(xwg + 16);
            const float4 t2 = *(const float4*)(xwg + 32);
            const float4 t3 = *(const float4*)(xwg + 48);
            __syncthreads();
            XWl[skq+ 0][sc]=t0.x; XWl[skq+ 1][sc]=t0.y; XWl[skq+ 2][sc]=t0.z; XWl[skq+ 3][sc]=t0.w;
            XWl[skq+16][sc]=t1.x; XWl[skq+17][sc]=t1.y; XWl[skq+18][sc]=t1.z; XWl[skq+19][sc]=t1.w;
            XWl[skq+32][sc]=t2.x; XWl[skq+33][sc]=t2.y; XWl[skq+34][sc]=t2.z; XWl[skq+35][sc]=t2.w;
            XWl[skq+48][sc]=t3.x; XWl[skq+49][sc]=t3.y; XWl[skq+50][sc]=t3.z; XWl[skq+51][sc]=t3.w;
            __syncthreads();
            #pragma unroll
            for (int k4 = 0; k4 < 16; ++k4) {
                const float4 yv = *(const float4*)&Yl[j][kcc + k4 * 4];
                const float* yp = (const float*)&yv;
                #pragma unroll
                for (int ss = 0; ss < 4; ++ss) {
                    const float4 xv = *(const float4*)&XWl[k4 * 4 + ss][c0];
                    sa[0] = fmaf(yp[ss], xv.x, sa[0]);
                    sa[1] = fmaf(yp[ss], xv.y, sa[1]);
                    sa[2] = fmaf(yp[ss], xv.z, sa[2]);
                    sa[3] = fmaf(yp[ss], xv.w, sa[3]);
                }
            }
        }
        float tmax = fmaxf(fmaxf(sa[0], sa[1]), fmaxf(sa[2], sa[3]));
        #pragma unroll
        for (int ww = 1; ww < 16; ww <<= 1) tmax = fmaxf(tmax, __shfl_xor(tmax, ww, 64));
        const float mnew = fmaxf(m, tmax);
        const float scale = __expf(m - mnew);
        const float p0 = __expf(sa[0] - mnew), p1 = __expf(sa[1] - mnew);
        const float p2 = __expf(sa[2] - mnew), p3 = __expf(sa[3] - mnew);
        float ts = p0 + p1 + p2 + p3;
        #pragma unroll
        for (int ww = 1; ww < 16; ww <<= 1) ts += __shfl_xor(ts, ww, 64);
        l = l * scale + ts; m = mnew;
        #pragma unroll
        for (int ii = 0; ii < 8; ++ii) {
            o[ii].x *= scale; o[ii].y *= scale; o[ii].z *= scale; o[ii].w *= scale;
        }
        *(float4*)&Pl[j][c0] = make_float4(p0, p1, p2, p3);
        for (int ccc = 0; ccc < 8; ++ccc) {
            const int xr = tid >> 5, xq = (tid & 31) * 4;
            const float* xg = x + xbase + (size_t)(xtt * 64 + ccc * 8 + xr) * D_DIM + xq;
            const float4 x0 = *(const float4*)(xg + 0);
            const float4 x1 = *(const float4*)(xg + 128);
            const float4 x2 = *(const float4*)(xg + 256);
            const float4 x3 = *(const float4*)(xg + 384);
            __syncthreads();
            *(float4*)&Xl[xr][xq +   0] = x0; *(float4*)&Xl[xr][xq + 128] = x1;
            *(float4*)&Xl[xr][xq + 256] = x2; *(float4*)&Xl[xr][xq + 384] = x3;
            __syncthreads();
            #pragma unroll
            for (int c = 0; c < 8; ++c) {
                const float pv = Pl[j][ccc * 8 + c];
                #pragma unroll
                for (int ii = 0; ii < 8; ++ii) {
                    const float4 xv = *(const float4*)&Xl[c][tc * 4 + 64 * ii];
                    o[ii].x = fmaf(pv, xv.x, o[ii].x); o[ii].y = fmaf(pv, xv.y, o[ii].y);
                    o[ii].z = fmaf(pv, xv.z, o[ii].z); o[ii].w = fmaf(pv, xv.w, o[ii].w);
                }
            }
        }
    }
    const float inv = 1.0f / l;
    float* og = out + (size_t)(b * LY + jtb * 16 + j) * D_DIM;
    #pragma unroll
    for (int ii = 0; ii < 8; ++ii) {
        float4 v = o[ii];
        v.x *= inv; v.y *= inv; v.z *= inv; v.w *= inv;
        *(float4*)(og + tc * 4 + 64 * ii) = v;
    }
}

// ---------------------------------------------------------------------------
extern "C" void kernel_launch(void* const* d_in, const int* in_sizes, int n_in,
                              void* d_out, int out_size, void* d_ws, size_t ws_size,
                              hipStream_t stream)
{
    const float* x  = (const float*)d_in[0];
    const float* y  = (const float*)d_in[1];
    const float* Wb = (const float*)d_in[2];
    float* out = (float*)d_out;

    // ws layout (bytes)
    const size_t SZ_BIG = 16777216;   // 8.4M bf16
    const size_t OFF_XFH = 0,         OFF_XFL = 16777216;
    const size_t OFF_YFH = 33554432,  OFF_YFL = 50331648;
    const size_t OFF_XTF = 67108864;
    const size_t OFF_XWH = 83886080,  OFF_XWL = 100663296;
    const size_t OFF_WFH = 117440512, OFF_WFL = 117964800;
    const size_t NEEDED = 118489088;
    (void)SZ_BIG;

    if (ws_size >= NEEDED) {
        char* ws = (char*)d_ws;
        unsigned short* xfh = (unsigned short*)(ws + OFF_XFH);
        unsigned short* xfl = (unsigned short*)(ws + OFF_XFL);
        unsigned short* yfh = (unsigned short*)(ws + OFF_YFH);
        unsigned short* yfl = (unsigned short*)(ws + OFF_YFL);
        unsigned short* xtf = (unsigned short*)(ws + OFF_XTF);
        unsigned short* xwfh = (unsigned short*)(ws + OFF_XWH);
        unsigned short* xwfl = (unsigned short*)(ws + OFF_XWL);
        unsigned short* wfh = (unsigned short*)(ws + OFF_WFH);
        unsigned short* wfl = (unsigned short*)(ws + OFF_WFL);

        repack_hilo_k<<<4096, 256, 0, stream>>>(x, xfh, xfl, 16384);
        repack_hilo_k<<<4096, 256, 0, stream>>>(y, yfh, yfl, 16384);
        repack_hilo_k<<<128, 256, 0, stream>>>(Wb, wfh, wfl, 512);
        dim3 gt(32, 8, 8);
        xt_repack_k<<<gt, 256, 0, stream>>>(x, xtf);
        dim3 g1(128, 8);
        xw_mfma_k<<<g1, 256, 0, stream>>>(xfh, xfl, wfh, wfl, xwfh, xwfl);
        dim3 g2(64, 8);
        flash_mfma_k<<<g2, 256, 0, stream>>>(yfh, yfl, xwfh, xwfl, xtf, out);
    } else {
        float* xw = (float*)d_ws;
        dim3 g1(NB * LX / 64, D_DIM / 64);
        xw_gemm_fb<<<g1, 256, 0, stream>>>(x, Wb, xw);
        dim3 g2(LY / 16, NB);
        flash_fb<<<g2, 256, 0, stream>>>(x, y, xw, out);
    }
}